// Round 3
// baseline (339.642 us; speedup 1.0000x reference)
//
#include <hip/hip_runtime.h>
#include <hip/hip_cooperative_groups.h>
#include <math.h>
#include <stdint.h>

#define B_ROWS 2048
#define D_DIM  512
#define V_COLS 32000
#define BM 128
#define BN 128
#define BK 64
#define KSTEPS (D_DIM / BK)             // 8
#define NCT    (V_COLS / BN)            // 250 col tiles
#define GRID   512                      // persistent blocks; >=2/CU co-resident guaranteed
#define NIDS   4096                     // R0 virtual id space (16 rt x 256 raw ct ids)
#define S_SC   30.0f
#define COS_M  0.8775825618903728f      // cos(0.5)
#define SIN_M  0.479425538604203f       // sin(0.5)

typedef float f32x4 __attribute__((ext_vector_type(4)));
typedef long  i64x2 __attribute__((ext_vector_type(2)));

__device__ __forceinline__ void load16_to_lds(const void* g, void* l) {
  __builtin_amdgcn_global_load_lds(
      (__attribute__((address_space(1))) void*)(g),
      (__attribute__((address_space(3))) void*)(l),
      16, 0, 0);
}

// ---------- single fused persistent cooperative kernel ----------
// R13: R11/R12's 256^2 phase-schedule rewrites both regressed (MfmaUtil 18-20% vs R0's
// 31% -- 1 block/CU loses the inter-block MFMA/VALU overlap that feeds R0's pipe).
// GEMM phase below is the PROVEN R0 128^2 body, byte-identical math, run persistently.
// The new lever: the 3-kernel version carried a stable ~84 us of non-GEMM time
// (norm roofline ~14 us + finish ~2 us + ~65 us launch/gap overhead). Fuse all three
// phases into ONE cooperative kernel with grid.sync() between phases:
//   phase 1: grid-strided row L2-normalize fp32->fp8 (fully coalesced r4[lane]/r4[lane+64])
//   phase 2: persistent R0 GEMM, 8 R0-id-space tiles per block (4096/512 exact)
//   phase 3: blocks 0..7 compute per-row loss + global mean
// grid.sync() provides the device-scope release/acquire for cross-XCD visibility of
// nx/nw (phase 1->2) and rowsum/lbl_logit (phase 2->3). Unlike the old R10 fused-finish
// regression (per-block __threadfence, serialized), the fence here runs twice total.
__global__ __launch_bounds__(256, 4)
void arc_fused_kernel(const float* __restrict__ x,
                      const float* __restrict__ W,
                      const int* __restrict__ labels,
                      uint8_t* __restrict__ nx,
                      uint8_t* __restrict__ nw,
                      float* __restrict__ rowsum,
                      float* __restrict__ lbl_logit,
                      float* __restrict__ out) {
  __shared__ uint8_t sA[2][BM * BK];   // 2 x 8 KB
  __shared__ uint8_t sB[2][BN * BK];   // 2 x 8 KB

  const int tid  = threadIdx.x;
  const int lane = tid & 63;
  const int wave = tid >> 6;

  // ================= phase 1: normalize + quantize; zero accumulators =================
  if (blockIdx.x == 0 && tid == 0) out[0] = 0.f;
  if (blockIdx.x < B_ROWS / 256) rowsum[blockIdx.x * 256 + tid] = 0.f;

  for (int r = blockIdx.x * 4 + wave; r < B_ROWS + V_COLS; r += GRID * 4) {
    const float* src;
    uint8_t* dst;
    if (r < B_ROWS) {                         // wave-uniform branch
      src = x + (size_t)r * D_DIM;
      dst = nx + (size_t)r * D_DIM;
    } else {
      src = W + (size_t)(r - B_ROWS) * D_DIM;
      dst = nw + (size_t)(r - B_ROWS) * D_DIM;
    }
    const float4* r4 = (const float4*)src;
    float4 v0 = r4[lane];                     // elems [4*lane, 4*lane+4)       coalesced
    float4 v1 = r4[lane + 64];                // elems [256+4*lane, ...)        coalesced
    float ss = v0.x*v0.x + v0.y*v0.y + v0.z*v0.z + v0.w*v0.w
             + v1.x*v1.x + v1.y*v1.y + v1.z*v1.z + v1.w*v1.w;
    #pragma unroll
    for (int off = 32; off >= 1; off >>= 1) ss += __shfl_xor(ss, off, 64);
    float inv = 1.0f / fmaxf(sqrtf(ss), 1e-12f);
    int p0 = __builtin_amdgcn_cvt_pk_fp8_f32(v0.x * inv, v0.y * inv, 0, false);
    p0     = __builtin_amdgcn_cvt_pk_fp8_f32(v0.z * inv, v0.w * inv, p0, true);
    int p1 = __builtin_amdgcn_cvt_pk_fp8_f32(v1.x * inv, v1.y * inv, 0, false);
    p1     = __builtin_amdgcn_cvt_pk_fp8_f32(v1.z * inv, v1.w * inv, p1, true);
    ((int*)dst)[lane]      = p0;
    ((int*)dst)[64 + lane] = p1;
  }

  cooperative_groups::this_grid().sync();     // nx/nw visible device-wide

  // ================= phase 2: persistent R0 GEMM (proven 87 us body) =================
  const int wm   = wave >> 1;
  const int wn   = wave & 1;
  const int quad = lane >> 4;
  const int l16  = lane & 15;
  const int srow = tid >> 2;
  const int jg   = (tid & 3) ^ ((srow >> 1) & 3);
  const int ldsOff0 = wave * 1024;
  const int ldsOff1 = 4096 + wave * 1024;
  const int cSlot = (quad ^ ((l16 >> 1) & 3)) << 4;
  const int aBase = (wm * 64 + l16) * BK + cSlot;   // + mi*16*BK
  const int bBase = (wn * 64 + l16) * BK + cSlot;   // + ni*16*BK

  for (int v = blockIdx.x; v < NIDS; v += GRID) {
    const int ct = ((v >> 7) << 3) | (v & 7);
    if (ct >= NCT) continue;                  // uniform skip of 96 invalid ids
    const int rt = (v >> 3) & 15;
    const int m0 = rt * BM;
    const int n0 = ct * BN;

    const uint8_t* gA = nx + (size_t)(m0 + srow) * D_DIM + jg * 16;
    const uint8_t* gB = nw + (size_t)(n0 + srow) * D_DIM + jg * 16;

    f32x4 acc[4][4];
    #pragma unroll
    for (int i = 0; i < 4; ++i)
      #pragma unroll
      for (int j = 0; j < 4; ++j) acc[i][j] = (f32x4){0.f, 0.f, 0.f, 0.f};

    // prologue: tile 0 -> buf 0 (buf0's last reads ended before the previous tile's
    // ks=7 opening __syncthreads, so this write is race-free in the persistent loop)
    load16_to_lds(gA,              &sA[0][ldsOff0]);
    load16_to_lds(gA + 64 * D_DIM, &sA[0][ldsOff1]);
    load16_to_lds(gB,              &sB[0][ldsOff0]);
    load16_to_lds(gB + 64 * D_DIM, &sB[0][ldsOff1]);

    #pragma unroll
    for (int ks = 0; ks < KSTEPS; ++ks) {
      __syncthreads();                        // prev compute done before overwrite
      if (ks + 1 < KSTEPS) {
        const int off = (ks + 1) * BK;
        const int nb  = (ks + 1) & 1;
        load16_to_lds(gA + off,              &sA[nb][ldsOff0]);
        load16_to_lds(gA + 64 * D_DIM + off, &sA[nb][ldsOff1]);
        load16_to_lds(gB + off,              &sB[nb][ldsOff0]);
        load16_to_lds(gB + 64 * D_DIM + off, &sB[nb][ldsOff1]);
      }
      __syncthreads();                        // tile ks resident

      const uint8_t* bA = sA[ks & 1];
      const uint8_t* bB = sB[ks & 1];
      i64x2 a2[4];
      #pragma unroll
      for (int mi = 0; mi < 4; ++mi)
        a2[mi] = *(const i64x2*)(bA + aBase + mi * 16 * BK);
      #pragma unroll
      for (int ni = 0; ni < 4; ++ni) {
        const i64x2 b2 = *(const i64x2*)(bB + bBase + ni * 16 * BK);
        #pragma unroll
        for (int mi = 0; mi < 4; ++mi) {
          acc[mi][ni] = __builtin_amdgcn_mfma_f32_16x16x32_fp8_fp8(a2[mi][0], b2[0], acc[mi][ni], 0, 0, 0);
          acc[mi][ni] = __builtin_amdgcn_mfma_f32_16x16x32_fp8_fp8(a2[mi][1], b2[1], acc[mi][ni], 0, 0, 0);
        }
      }
    }

    // Epilogue (R4-proven). C/D layout: col = lane&15, row = quad*4 + reg.
    const int lblv = labels[m0 + wm * 64 + lane];
    #pragma unroll
    for (int mi = 0; mi < 4; ++mi) {
      #pragma unroll
      for (int r = 0; r < 4; ++r) {
        const int rw   = mi * 16 + quad * 4 + r;
        const int grow = m0 + wm * 64 + rw;
        const int lbl  = __shfl(lblv, rw, 64);
        float rsum = 0.f;
        #pragma unroll
        for (int ni = 0; ni < 4; ++ni) {
          float c = acc[mi][ni][r];
          const int gcol = n0 + wn * 64 + ni * 16 + l16;
          if (gcol == lbl) {
            float sy  = sqrtf(fminf(1.f, fmaxf(0.f, 1.f - c * c)));
            float phi = c * COS_M - sy * SIN_M;
            lbl_logit[grow] = S_SC * phi;     // exactly one lane grid-wide
            c = phi;
          }
          rsum += __expf(S_SC * c - 30.0f);   // fixed shift: logits in [-30,30]
        }
        #pragma unroll
        for (int off = 1; off < 16; off <<= 1)
          rsum += __shfl_xor(rsum, off, 64);
        if (l16 == 0) atomicAdd(&rowsum[grow], rsum);
      }
    }
  }

  cooperative_groups::this_grid().sync();     // rowsum/lbl_logit complete device-wide

  // ================= phase 3: per-row loss + global mean (blocks 0..7) =================
  if (blockIdx.x < B_ROWS / 256) {
    const int row = blockIdx.x * 256 + tid;
    float vv = (30.0f + logf(rowsum[row]) - lbl_logit[row]) * (1.0f / (float)B_ROWS);
    #pragma unroll
    for (int off = 32; off >= 1; off >>= 1) vv += __shfl_xor(vv, off, 64);
    float* wsum = (float*)sA;                 // reuse LDS
    if (lane == 0) wsum[wave] = vv;
    __syncthreads();
    if (tid == 0) atomicAdd(out, wsum[0] + wsum[1] + wsum[2] + wsum[3]);
  }
}

// ---------- launch ----------
extern "C" void kernel_launch(void* const* d_in, const int* in_sizes, int n_in,
                              void* d_out, int out_size, void* d_ws, size_t ws_size,
                              hipStream_t stream) {
  const float* x      = (const float*)d_in[0];
  const float* W      = (const float*)d_in[1];
  const int*   labels = (const int*)d_in[2];
  float* out = (float*)d_out;

  char* ws = (char*)d_ws;
  uint8_t* nx = (uint8_t*)ws;                                       // 1 MB
  uint8_t* nw = (uint8_t*)(ws + (size_t)B_ROWS * D_DIM);            // 16.4 MB
  char* p = ws + (size_t)B_ROWS * D_DIM + (size_t)V_COLS * D_DIM;
  float* rowsum    = (float*)p;  p += (size_t)B_ROWS * 4;           // 8 KB
  float* lbl_logit = (float*)p;                                     // 8 KB

  void* args[] = {(void*)&x, (void*)&W, (void*)&labels, (void*)&nx, (void*)&nw,
                  (void*)&rowsum, (void*)&lbl_logit, (void*)&out};
  hipLaunchCooperativeKernel(reinterpret_cast<void*>(arc_fused_kernel),
                             dim3(GRID), dim3(256), args, 0, stream);
}

// Round 4
// 176.847 us; speedup vs baseline: 1.9205x; 1.9205x over previous
//
#include <hip/hip_runtime.h>
#include <math.h>
#include <stdint.h>

#define B_ROWS 2048
#define D_DIM  512
#define V_COLS 32000
#define BM 128
#define BN 128
#define BK 64
#define KSTEPS (D_DIM / BK)             // 8
#define NCT    (V_COLS / BN)            // 250 col tiles
#define S_SC   30.0f
#define COS_M  0.8775825618903728f      // cos(0.5)
#define SIN_M  0.479425538604203f       // sin(0.5)

typedef float f32x4 __attribute__((ext_vector_type(4)));
typedef long  i64x2 __attribute__((ext_vector_type(2)));

__device__ __forceinline__ void load16_to_lds(const void* g, void* l) {
  __builtin_amdgcn_global_load_lds(
      (__attribute__((address_space(1))) void*)(g),
      (__attribute__((address_space(3))) void*)(l),
      16, 0, 0);
}

// ---------- kernel 1: fused row L2-normalize (x,W) fp32 -> fp8 e4m3, + zero rowsum/out ----------
__global__ void fused_norm_kernel(const float* __restrict__ x,
                                  const float* __restrict__ W,
                                  uint8_t* __restrict__ nx,
                                  uint8_t* __restrict__ nw,
                                  float* __restrict__ rowsum,
                                  float* __restrict__ out) {
  if (blockIdx.x == 0 && threadIdx.x == 0) out[0] = 0.f;
  if (blockIdx.x < B_ROWS / 256) rowsum[blockIdx.x * 256 + threadIdx.x] = 0.f;
  const int lane = threadIdx.x & 63;
  const int wave = threadIdx.x >> 6;
  const int gr   = blockIdx.x * 4 + wave;
  const float* src;
  uint8_t* dst;
  if (gr < B_ROWS) {
    src = x + (size_t)gr * D_DIM;
    dst = nx + (size_t)gr * D_DIM;
  } else {
    src = W + (size_t)(gr - B_ROWS) * D_DIM;
    dst = nw + (size_t)(gr - B_ROWS) * D_DIM;
  }
  const float4* r4 = (const float4*)src;
  float4 v0 = r4[2 * lane];
  float4 v1 = r4[2 * lane + 1];
  float ss = v0.x*v0.x + v0.y*v0.y + v0.z*v0.z + v0.w*v0.w
           + v1.x*v1.x + v1.y*v1.y + v1.z*v1.z + v1.w*v1.w;
  #pragma unroll
  for (int off = 32; off >= 1; off >>= 1) ss += __shfl_xor(ss, off, 64);
  float inv = 1.0f / fmaxf(sqrtf(ss), 1e-12f);
  int p0 = __builtin_amdgcn_cvt_pk_fp8_f32(v0.x * inv, v0.y * inv, 0, false);
  p0     = __builtin_amdgcn_cvt_pk_fp8_f32(v0.z * inv, v0.w * inv, p0, true);
  int p1 = __builtin_amdgcn_cvt_pk_fp8_f32(v1.x * inv, v1.y * inv, 0, false);
  p1     = __builtin_amdgcn_cvt_pk_fp8_f32(v1.z * inv, v1.w * inv, p1, true);
  ((int2*)dst)[lane] = make_int2(p0, p1);
}

// ---------- kernel 2: fp8 GEMM (nx @ nW^T), R0 geometry + counted-vmcnt triple buffer ----------
// R14: R3's fusion falsified the launch-gap theory (fixed ~86 us harness overhead,
// dispatch-count independent). Back to the proven R0 128^2 / 4-wave / 4096-block
// structure (87 us, MfmaUtil 31%), changing ONLY the sync structure:
//   R0 stall: __syncthreads() => s_waitcnt vmcnt(0) drains the JUST-ISSUED
//   global_load_lds every K-step (~200+ cyc L2 latency on the critical path;
//   155 MFMA cyc / (155+200+bar) = the measured 31%).
//   Fix: 3 LDS buffers (48 KB, keeps 3 blocks/CU = R0's measured occupancy) + raw
//   s_barrier + counted vmcnt(n): step ks waits only on loads issued at ks-2
//   (long landed); the 8 loads for ks+1/ks+2 stay in flight across the barrier.
// Race audit: stage target (ks+2)%3 last READ at step ks-1; those ds_reads retire
// before their consuming MFMAs, which issue before barrier 1 of step ks (WAR safe).
// RAW: per-wave vmcnt(n) then barrier => all waves' tile-ks loads landed before any
// wave computes. n = 4*[(ks+1<8)] + 4*[(ks+2<8)] = 8,8,8,8,8,8,4,0.
// Everything else (swizzles, epilogue, grid) is byte-identical to R0.
__global__ __launch_bounds__(256, 3)
void arc_gemm_kernel(const uint8_t* __restrict__ nx,
                     const uint8_t* __restrict__ nw,
                     const int* __restrict__ labels,
                     float* __restrict__ rowsum,
                     float* __restrict__ lbl_logit) {
  __shared__ uint8_t sA[3][BM * BK];   // 3 x 8 KB
  __shared__ uint8_t sB[3][BN * BK];   // 3 x 8 KB  (48 KB total, 3 blocks/CU)

  const int id = blockIdx.x;
  const int ct = ((id >> 7) << 3) | (id & 7);
  if (ct >= NCT) return;
  const int rt = (id >> 3) & 15;
  const int m0 = rt * BM;
  const int n0 = ct * BN;

  const int tid  = threadIdx.x;
  const int wave = tid >> 6;
  const int lane = tid & 63;
  const int wm   = wave >> 1;
  const int wn   = wave & 1;
  const int quad = lane >> 4;
  const int l16  = lane & 15;

  // staging: inst i covers rows i*64 + (tid>>2); slot tid&3 <- global 16B chunk jg.
  const int srow = tid >> 2;
  const int jg   = (tid & 3) ^ ((srow >> 1) & 3);
  const uint8_t* gA = nx + (size_t)(m0 + srow) * D_DIM + jg * 16;
  const uint8_t* gB = nw + (size_t)(n0 + srow) * D_DIM + jg * 16;
  const int ldsOff0 = wave * 1024;          // wave-uniform LDS byte bases
  const int ldsOff1 = 4096 + wave * 1024;

  // frag reads: row stride 64 B, 16B slot XOR swizzle (measured-zero-conflict math)
  const int cSlot = (quad ^ ((l16 >> 1) & 3)) << 4;
  const int aBase = (wm * 64 + l16) * BK + cSlot;   // + mi*16*BK
  const int bBase = (wn * 64 + l16) * BK + cSlot;   // + ni*16*BK

  f32x4 acc[4][4];
  #pragma unroll
  for (int i = 0; i < 4; ++i)
    #pragma unroll
    for (int j = 0; j < 4; ++j) acc[i][j] = (f32x4){0.f, 0.f, 0.f, 0.f};

#define STAGE(buf, t) do {                                        \
    const int _o = (t) * BK;                                      \
    load16_to_lds(gA + _o,              &sA[(buf)][ldsOff0]);     \
    load16_to_lds(gA + 64 * D_DIM + _o, &sA[(buf)][ldsOff1]);     \
    load16_to_lds(gB + _o,              &sB[(buf)][ldsOff0]);     \
    load16_to_lds(gB + 64 * D_DIM + _o, &sB[(buf)][ldsOff1]);     \
  } while (0)

  // prologue: tiles 0,1 in flight (8 loads/thread)
  STAGE(0, 0);
  STAGE(1, 1);

  #pragma unroll
  for (int ks = 0; ks < KSTEPS; ++ks) {
    // barrier 1: all waves finished READING buf[(ks+2)%3] (during step ks-1)
    __builtin_amdgcn_sched_barrier(0);
    __builtin_amdgcn_s_barrier();
    __builtin_amdgcn_sched_barrier(0);
    if (ks + 2 < KSTEPS) STAGE((ks + 2) % 3, ks + 2);
    // counted wait: tile ks's 4 loads (issued at step ks-2) must land;
    // newer stages (ks+1, ks+2 if they exist) stay in flight.
    if (ks < KSTEPS - 2)       asm volatile("s_waitcnt vmcnt(8)" ::: "memory");
    else if (ks == KSTEPS - 2) asm volatile("s_waitcnt vmcnt(4)" ::: "memory");
    else                       asm volatile("s_waitcnt vmcnt(0)" ::: "memory");
    __builtin_amdgcn_sched_barrier(0);
    __builtin_amdgcn_s_barrier();             // barrier 2: tile ks resident for all
    __builtin_amdgcn_sched_barrier(0);

    const uint8_t* bA = sA[ks % 3];
    const uint8_t* bB = sB[ks % 3];
    i64x2 a2[4];
    #pragma unroll
    for (int mi = 0; mi < 4; ++mi)
      a2[mi] = *(const i64x2*)(bA + aBase + mi * 16 * BK);
    #pragma unroll
    for (int ni = 0; ni < 4; ++ni) {
      const i64x2 b2 = *(const i64x2*)(bB + bBase + ni * 16 * BK);
      #pragma unroll
      for (int mi = 0; mi < 4; ++mi) {
        acc[mi][ni] = __builtin_amdgcn_mfma_f32_16x16x32_fp8_fp8(a2[mi][0], b2[0], acc[mi][ni], 0, 0, 0);
        acc[mi][ni] = __builtin_amdgcn_mfma_f32_16x16x32_fp8_fp8(a2[mi][1], b2[1], acc[mi][ni], 0, 0, 0);
      }
    }
  }
#undef STAGE

  // Epilogue (R4-proven). C/D layout: col = lane&15, row = quad*4 + reg.
  const int lblv = labels[m0 + wm * 64 + lane];
  #pragma unroll
  for (int mi = 0; mi < 4; ++mi) {
    #pragma unroll
    for (int r = 0; r < 4; ++r) {
      const int rw   = mi * 16 + quad * 4 + r;
      const int grow = m0 + wm * 64 + rw;
      const int lbl  = __shfl(lblv, rw, 64);
      float rsum = 0.f;
      #pragma unroll
      for (int ni = 0; ni < 4; ++ni) {
        float c = acc[mi][ni][r];
        const int gcol = n0 + wn * 64 + ni * 16 + l16;
        if (gcol == lbl) {
          float sy  = sqrtf(fminf(1.f, fmaxf(0.f, 1.f - c * c)));
          float phi = c * COS_M - sy * SIN_M;
          lbl_logit[grow] = S_SC * phi;       // exactly one lane grid-wide
          c = phi;
        }
        rsum += __expf(S_SC * c - 30.0f);     // fixed shift: logits in [-30,30]
      }
      #pragma unroll
      for (int off = 1; off < 16; off <<= 1)
        rsum += __shfl_xor(rsum, off, 64);
      if (l16 == 0) atomicAdd(&rowsum[grow], rsum);
    }
  }
}

// ---------- kernel 3: per-row loss + global mean ----------
__global__ void arc_finish_kernel(const float* __restrict__ rowsum,
                                  const float* __restrict__ lbl_logit,
                                  float* __restrict__ out) {
  const int row  = blockIdx.x * 256 + threadIdx.x;   // 8 blocks x 256
  const int lane = threadIdx.x & 63;
  const int wave = threadIdx.x >> 6;
  float v = (30.0f + logf(rowsum[row]) - lbl_logit[row]) * (1.0f / (float)B_ROWS);
  #pragma unroll
  for (int off = 32; off >= 1; off >>= 1) v += __shfl_xor(v, off, 64);
  __shared__ float wsum[4];
  if (lane == 0) wsum[wave] = v;
  __syncthreads();
  if (threadIdx.x == 0) atomicAdd(out, wsum[0] + wsum[1] + wsum[2] + wsum[3]);
}

// ---------- launch ----------
extern "C" void kernel_launch(void* const* d_in, const int* in_sizes, int n_in,
                              void* d_out, int out_size, void* d_ws, size_t ws_size,
                              hipStream_t stream) {
  const float* x      = (const float*)d_in[0];
  const float* W      = (const float*)d_in[1];
  const int*   labels = (const int*)d_in[2];
  float* out = (float*)d_out;

  char* ws = (char*)d_ws;
  uint8_t* nx = (uint8_t*)ws;                                       // 1 MB
  uint8_t* nw = (uint8_t*)(ws + (size_t)B_ROWS * D_DIM);            // 16.4 MB
  char* p = ws + (size_t)B_ROWS * D_DIM + (size_t)V_COLS * D_DIM;
  float* rowsum    = (float*)p;  p += (size_t)B_ROWS * 4;           // 8 KB
  float* lbl_logit = (float*)p;                                     // 8 KB

  hipLaunchKernelGGL(fused_norm_kernel, dim3((B_ROWS + V_COLS) / 4), dim3(256), 0, stream,
                     x, W, nx, nw, rowsum, out);
  hipLaunchKernelGGL(arc_gemm_kernel, dim3(32 * 16 * 8), dim3(256), 0, stream,
                     nx, nw, labels, rowsum, lbl_logit);
  hipLaunchKernelGGL(arc_finish_kernel, dim3(B_ROWS / 256), dim3(256), 0, stream,
                     rowsum, lbl_logit, out);
}